// Round 6
// baseline (134.125 us; speedup 1.0000x reference)
//
#include <hip/hip_runtime.h>

#define N_ATOMS 10000
#define N_DIH   8000
#define NB      2048          // frames (innermost, contiguous)
#define EPS     1e-12f

typedef float f4_t __attribute__((ext_vector_type(4)));

// R1's PASSING math, with exactly two value-safe changes:
//  (1) FINAL normalize only: sqrt+precise-div -> v_rsq_f32. Sign-exact
//      (inv>0 always, sp1/sp2 bits identical to R1) and magnitude-only
//      ~2ulp fp32 => invisible at the 2e-2 threshold. The three a-vector
//      normalizations KEEP IEEE sqrtf + IEEE division (R5 proved a 1-ulp
//      perturbation there flips signs at near-degenerate dihedrals).
//  (2) Block->work remap: phase by frame-half so each phase's gather
//      working set (123 MB) fits L3; bit-identical outputs.
__global__ __launch_bounds__(256) void dihedral_kernel(
    const float* __restrict__ x,      // (N_ATOMS, 3, NB)
    const int*   __restrict__ atoms,  // (N_DIH, 4)
    float*       __restrict__ out)    // (2*N_DIH, NB)
{
    const int bid  = blockIdx.x;
    const int d    = (bid < N_DIH) ? bid : (bid - N_DIH);
    const int half = (bid < N_DIH) ? 0 : 1024;
    const int b    = half + (threadIdx.x << 2);   // frame base, 4 frames/thread

    const int4 aidx = *reinterpret_cast<const int4*>(atoms + d * 4);
    const int ai[4] = {aidx.x, aidx.y, aidx.z, aidx.w};

    // g[atom][coord] : 4 frames packed in a float4
    float4 g[4][3];
#pragma unroll
    for (int j = 0; j < 4; ++j) {
        const float* base = x + (size_t)ai[j] * (3 * NB) + b;
#pragma unroll
        for (int c = 0; c < 3; ++c) {
            g[j][c] = *reinterpret_cast<const float4*>(base + c * NB);
        }
    }

    f4_t v0, v1;
#pragma unroll
    for (int k = 0; k < 4; ++k) {
        float p[4][3];
#pragma unroll
        for (int j = 0; j < 4; ++j) {
            p[j][0] = reinterpret_cast<const float*>(&g[j][0])[k];
            p[j][1] = reinterpret_cast<const float*>(&g[j][1])[k];
            p[j][2] = reinterpret_cast<const float*>(&g[j][2])[k];
        }

        float a12[3], a23[3], a34[3];
#pragma unroll
        for (int c = 0; c < 3; ++c) {
            a12[c] = p[1][c] - p[0][c];
            a23[c] = p[2][c] - p[1][c];
            a34[c] = p[3][c] - p[2][c];
        }
        // normalize exactly as R1 (IEEE sqrt + IEEE division) — proven
        // sign-critical at near-degenerate dihedrals (R5 bisection).
        {
            float n12 = sqrtf(a12[0]*a12[0] + a12[1]*a12[1] + a12[2]*a12[2]);
            float n23 = sqrtf(a23[0]*a23[0] + a23[1]*a23[1] + a23[2]*a23[2]);
            float n34 = sqrtf(a34[0]*a34[0] + a34[1]*a34[1] + a34[2]*a34[2]);
            float i12 = 1.0f / fmaxf(n12, EPS);
            float i23 = 1.0f / fmaxf(n23, EPS);
            float i34 = 1.0f / fmaxf(n34, EPS);
#pragma unroll
            for (int c = 0; c < 3; ++c) { a12[c] *= i12; a23[c] *= i23; a34[c] *= i34; }
        }

        // vp1 = a12 x a23 ; vp2 = a23 x a34 ; vp3 = vp1 x a23  (as R1)
        float vp1[3], vp2[3], vp3[3];
        vp1[0] = a12[1]*a23[2] - a12[2]*a23[1];
        vp1[1] = a12[2]*a23[0] - a12[0]*a23[2];
        vp1[2] = a12[0]*a23[1] - a12[1]*a23[0];

        vp2[0] = a23[1]*a34[2] - a23[2]*a34[1];
        vp2[1] = a23[2]*a34[0] - a23[0]*a34[2];
        vp2[2] = a23[0]*a34[1] - a23[1]*a34[0];

        vp3[0] = vp1[1]*a23[2] - vp1[2]*a23[1];
        vp3[1] = vp1[2]*a23[0] - vp1[0]*a23[2];
        vp3[2] = vp1[0]*a23[1] - vp1[1]*a23[0];

        float sp1 = vp1[0]*vp2[0] + vp1[1]*vp2[1] + vp1[2]*vp2[2];
        float sp2 = vp3[0]*vp2[0] + vp3[1]*vp2[1] + vp3[2]*vp2[2];

        // FINAL normalize: magnitude-only rsq approximation (sign-exact).
        // 1/max(sqrt(s2),1e-12) == rsq(max(s2,1e-24)) to ~1ulp, both branches.
        float s2  = sp1*sp1 + sp2*sp2;
        float inv = __builtin_amdgcn_rsqf(fmaxf(s2, 1e-24f));
        v0[k] = -sp2 * inv;   // st[0]
        v1[k] =  sp1 * inv;   // st[1]
    }

    // write-once output: non-temporal keeps the 128 MB write stream from
    // evicting the phase's 123 MB gather working set out of L3
    __builtin_nontemporal_store(v0, reinterpret_cast<f4_t*>(out + (size_t)d * NB + b));
    __builtin_nontemporal_store(v1, reinterpret_cast<f4_t*>(out + (size_t)(N_DIH + d) * NB + b));
}

extern "C" void kernel_launch(void* const* d_in, const int* in_sizes, int n_in,
                              void* d_out, int out_size, void* d_ws, size_t ws_size,
                              hipStream_t stream) {
    const float* x     = (const float*)d_in[0];
    const int*   atoms = (const int*)d_in[1];
    float*       out   = (float*)d_out;

    const int grid  = 2 * N_DIH;   // two frame-half phases x 8000 dihedrals
    const int block = 256;         // 256 threads x 4 frames = 1024-frame half
    dihedral_kernel<<<grid, block, 0, stream>>>(x, atoms, out);
}

// Round 7
// 132.949 us; speedup vs baseline: 1.0088x; 1.0088x over previous
//
#include <hip/hip_runtime.h>

#define N_ATOMS 10000
#define N_DIH   8000
#define NB      2048          // frames (innermost, contiguous)
#define EPS     1e-12f

typedef float f4_t __attribute__((ext_vector_type(4)));

// Math is BIT-IDENTICAL to round 6 (passing, absmax 0.0039).
// Only change: force all 12 gather float4s to be simultaneously in flight
// (asm keep-alive) — R6's VGPR_Count=32 proved the compiler was batching
// the gathers 2-3 at a time with a full memory round-trip between batches.
__global__ __launch_bounds__(256) void dihedral_kernel(
    const float* __restrict__ x,      // (N_ATOMS, 3, NB)
    const int*   __restrict__ atoms,  // (N_DIH, 4)
    float*       __restrict__ out)    // (2*N_DIH, NB)
{
    const int bid  = blockIdx.x;
    const int d    = (bid < N_DIH) ? bid : (bid - N_DIH);
    const int half = (bid < N_DIH) ? 0 : 1024;
    const int b    = half + (threadIdx.x << 2);   // frame base, 4 frames/thread

    const int4 aidx = *reinterpret_cast<const int4*>(atoms + d * 4);
    const int ai[4] = {aidx.x, aidx.y, aidx.z, aidx.w};

    // g[atom][coord] : 4 frames packed per register quad
    f4_t g[4][3];
#pragma unroll
    for (int j = 0; j < 4; ++j) {
        const float* base = x + (size_t)ai[j] * (3 * NB) + b;
#pragma unroll
        for (int c = 0; c < 3; ++c) {
            g[j][c] = *reinterpret_cast<const f4_t*>(base + c * NB);
        }
    }
    // Keep-alive: all 12 load results must materialize HERE -> compiler
    // issues all 12 global_load_dwordx4 back-to-back, one waitcnt, then
    // computes. 4x memory-level parallelism vs the 32-VGPR schedule.
    asm volatile("" :
        "+v"(g[0][0]), "+v"(g[0][1]), "+v"(g[0][2]),
        "+v"(g[1][0]), "+v"(g[1][1]), "+v"(g[1][2]),
        "+v"(g[2][0]), "+v"(g[2][1]), "+v"(g[2][2]),
        "+v"(g[3][0]), "+v"(g[3][1]), "+v"(g[3][2]));

    f4_t v0, v1;
#pragma unroll
    for (int k = 0; k < 4; ++k) {
        float p[4][3];
#pragma unroll
        for (int j = 0; j < 4; ++j) {
            p[j][0] = g[j][0][k];
            p[j][1] = g[j][1][k];
            p[j][2] = g[j][2][k];
        }

        float a12[3], a23[3], a34[3];
#pragma unroll
        for (int c = 0; c < 3; ++c) {
            a12[c] = p[1][c] - p[0][c];
            a23[c] = p[2][c] - p[1][c];
            a34[c] = p[3][c] - p[2][c];
        }
        // normalize exactly as R1/R6 (IEEE sqrt + IEEE division) — proven
        // sign-critical at near-degenerate dihedrals (R5 bisection).
        {
            float n12 = sqrtf(a12[0]*a12[0] + a12[1]*a12[1] + a12[2]*a12[2]);
            float n23 = sqrtf(a23[0]*a23[0] + a23[1]*a23[1] + a23[2]*a23[2]);
            float n34 = sqrtf(a34[0]*a34[0] + a34[1]*a34[1] + a34[2]*a34[2]);
            float i12 = 1.0f / fmaxf(n12, EPS);
            float i23 = 1.0f / fmaxf(n23, EPS);
            float i34 = 1.0f / fmaxf(n34, EPS);
#pragma unroll
            for (int c = 0; c < 3; ++c) { a12[c] *= i12; a23[c] *= i23; a34[c] *= i34; }
        }

        // vp1 = a12 x a23 ; vp2 = a23 x a34 ; vp3 = vp1 x a23  (as R1/R6)
        float vp1[3], vp2[3], vp3[3];
        vp1[0] = a12[1]*a23[2] - a12[2]*a23[1];
        vp1[1] = a12[2]*a23[0] - a12[0]*a23[2];
        vp1[2] = a12[0]*a23[1] - a12[1]*a23[0];

        vp2[0] = a23[1]*a34[2] - a23[2]*a34[1];
        vp2[1] = a23[2]*a34[0] - a23[0]*a34[2];
        vp2[2] = a23[0]*a34[1] - a23[1]*a34[0];

        vp3[0] = vp1[1]*a23[2] - vp1[2]*a23[1];
        vp3[1] = vp1[2]*a23[0] - vp1[0]*a23[2];
        vp3[2] = vp1[0]*a23[1] - vp1[1]*a23[0];

        float sp1 = vp1[0]*vp2[0] + vp1[1]*vp2[1] + vp1[2]*vp2[2];
        float sp2 = vp3[0]*vp2[0] + vp3[1]*vp2[1] + vp3[2]*vp2[2];

        // FINAL normalize: magnitude-only rsq approximation (sign-exact,
        // proven passing in R6).
        float s2  = sp1*sp1 + sp2*sp2;
        float inv = __builtin_amdgcn_rsqf(fmaxf(s2, 1e-24f));
        v0[k] = -sp2 * inv;   // st[0]
        v1[k] =  sp1 * inv;   // st[1]
    }

    // write-once output: non-temporal (value-identical)
    __builtin_nontemporal_store(v0, reinterpret_cast<f4_t*>(out + (size_t)d * NB + b));
    __builtin_nontemporal_store(v1, reinterpret_cast<f4_t*>(out + (size_t)(N_DIH + d) * NB + b));
}

extern "C" void kernel_launch(void* const* d_in, const int* in_sizes, int n_in,
                              void* d_out, int out_size, void* d_ws, size_t ws_size,
                              hipStream_t stream) {
    const float* x     = (const float*)d_in[0];
    const int*   atoms = (const int*)d_in[1];
    float*       out   = (float*)d_out;

    const int grid  = 2 * N_DIH;   // two frame-half phases x 8000 dihedrals
    const int block = 256;         // 256 threads x 4 frames = 1024-frame half
    dihedral_kernel<<<grid, block, 0, stream>>>(x, atoms, out);
}